// Round 1
// baseline (843.087 us; speedup 1.0000x reference)
//
#include <hip/hip_runtime.h>
#include <hip/hip_bf16.h>

#define N_NODES 20000
#define N_EDGES 200000
#define DIN 256
#define DOUT 256
#define NH 2
#define HC 128
#define TDIM 100
#define MSGD 156
#define PDROP 0.1f

typedef __hip_bfloat16 bf16;

// ---- ordered-uint encoding for float atomicMax (handles negatives) ----
__device__ __forceinline__ unsigned fkey(float f) {
  unsigned u = __float_as_uint(f);
  return (u & 0x80000000u) ? ~u : (u | 0x80000000u);
}
__device__ __forceinline__ float fkey_dec(unsigned k) {
  return (k & 0x80000000u) ? __uint_as_float(k ^ 0x80000000u)
                           : __uint_as_float(~k);
}

__global__ void init_md(unsigned* __restrict__ mkeys, float* __restrict__ denom) {
  int i = blockIdx.x * blockDim.x + threadIdx.x;
  if (i < N_NODES * NH) {
    mkeys[i] = 0x007FFFFFu;  // fkey(-inf)
    denom[i] = 0.f;
  }
}

// ---- node projection GEMM: C[M,256] = x[M,256] @ W[256,256] + bias ----
// 64x64 tile, 256 threads (16x16), 4x4 microtile, K-step 16.
__global__ __launch_bounds__(256) void gemm_nodes(
    const float* __restrict__ x, const float* __restrict__ W,
    const float* __restrict__ bias, float* __restrict__ out) {
  __shared__ float As[16][68];  // [k][m], padded for bank conflicts + 16B align
  __shared__ float Bs[16][64];  // [k][n]
  const int tid = threadIdx.x;
  const int tx = tid & 15, ty = tid >> 4;
  const int row0 = blockIdx.x * 64, col0 = blockIdx.y * 64;
  float acc[4][4] = {};
  for (int k0 = 0; k0 < DIN; k0 += 16) {
#pragma unroll
    for (int i = 0; i < 4; i++) {
      int l = tid + i * 256;
      int kk = l & 15, m = l >> 4;
      int r = row0 + m;
      As[kk][m] = (r < N_NODES) ? x[(size_t)r * DIN + k0 + kk] : 0.f;
    }
#pragma unroll
    for (int i = 0; i < 4; i++) {
      int l = tid + i * 256;
      int n = l & 63, kk = l >> 6;
      Bs[kk][n] = W[(size_t)(k0 + kk) * DOUT + col0 + n];
    }
    __syncthreads();
#pragma unroll
    for (int kk = 0; kk < 16; kk++) {
      float a[4], b[4];
#pragma unroll
      for (int i = 0; i < 4; i++) a[i] = As[kk][ty * 4 + i];
#pragma unroll
      for (int j = 0; j < 4; j++) b[j] = Bs[kk][tx * 4 + j];
#pragma unroll
      for (int i = 0; i < 4; i++)
#pragma unroll
        for (int j = 0; j < 4; j++) acc[i][j] += a[i] * b[j];
    }
    __syncthreads();
  }
#pragma unroll
  for (int i = 0; i < 4; i++) {
    int r = row0 + ty * 4 + i;
    if (r < N_NODES) {
#pragma unroll
      for (int j = 0; j < 4; j++) {
        int c = col0 + tx * 4 + j;
        out[(size_t)r * DOUT + c] = acc[i][j] + bias[c];
      }
    }
  }
}

// ---- edge GEMM: e[E,256] = [cos(rel_t*tw+tb) | msg] @ We + be  (bf16 out) ----
__global__ __launch_bounds__(256) void gemm_edges(
    const float* __restrict__ last_update, const int* __restrict__ ei,
    const float* __restrict__ t, const float* __restrict__ msg,
    const float* __restrict__ time_w, const float* __restrict__ time_b,
    const float* __restrict__ We, const float* __restrict__ be,
    bf16* __restrict__ e_out) {
  __shared__ float As[16][68];
  __shared__ float Bs[16][64];
  __shared__ float relt[64];
  const int tid = threadIdx.x;
  const int tx = tid & 15, ty = tid >> 4;
  const int row0 = blockIdx.x * 64, col0 = blockIdx.y * 64;
  if (tid < 64) {
    int eidx = row0 + tid;
    relt[tid] = last_update[ei[eidx]] - t[eidx];
  }
  __syncthreads();
  float acc[4][4] = {};
  for (int k0 = 0; k0 < 256; k0 += 16) {
#pragma unroll
    for (int i = 0; i < 4; i++) {
      int l = tid + i * 256;
      int kk = l & 15, m = l >> 4;
      int kc = k0 + kk;
      float a;
      if (kc < TDIM)
        a = __cosf(relt[m] * time_w[kc] + time_b[kc]);
      else
        a = msg[(size_t)(row0 + m) * MSGD + (kc - TDIM)];
      As[kk][m] = a;
    }
#pragma unroll
    for (int i = 0; i < 4; i++) {
      int l = tid + i * 256;
      int n = l & 63, kk = l >> 6;
      Bs[kk][n] = We[(size_t)(k0 + kk) * DOUT + col0 + n];
    }
    __syncthreads();
#pragma unroll
    for (int kk = 0; kk < 16; kk++) {
      float a[4], b[4];
#pragma unroll
      for (int i = 0; i < 4; i++) a[i] = As[kk][ty * 4 + i];
#pragma unroll
      for (int j = 0; j < 4; j++) b[j] = Bs[kk][tx * 4 + j];
#pragma unroll
      for (int i = 0; i < 4; i++)
#pragma unroll
        for (int j = 0; j < 4; j++) acc[i][j] += a[i] * b[j];
    }
    __syncthreads();
  }
#pragma unroll
  for (int i = 0; i < 4; i++) {
    int r = row0 + ty * 4 + i;
#pragma unroll
    for (int j = 0; j < 4; j++) {
      int c = col0 + tx * 4 + j;
      e_out[(size_t)r * DOUT + c] = __float2bfloat16(acc[i][j] + be[c]);
    }
  }
}

// ---- per-edge attention logits + segment max (one wave per edge) ----
__global__ __launch_bounds__(256) void alpha_max(
    const float* __restrict__ q, const float* __restrict__ k,
    const bf16* __restrict__ e, const int* __restrict__ ei,
    const float* __restrict__ u_edge, float* __restrict__ alpha,
    unsigned* __restrict__ mkeys) {
  int wid = (blockIdx.x * blockDim.x + threadIdx.x) >> 6;
  int lane = threadIdx.x & 63;
  if (wid >= N_EDGES) return;
  int s = ei[wid];
  int d = ei[N_EDGES + wid];
  const float* qd = q + (size_t)d * DOUT;
  const float* ks = k + (size_t)s * DOUT;
  const bf16* ee = e + (size_t)wid * DOUT;
  float s0 = qd[lane] * (ks[lane] + __bfloat162float(ee[lane])) +
             qd[lane + 64] * (ks[lane + 64] + __bfloat162float(ee[lane + 64]));
  float s1 = qd[lane + 128] * (ks[lane + 128] + __bfloat162float(ee[lane + 128])) +
             qd[lane + 192] * (ks[lane + 192] + __bfloat162float(ee[lane + 192]));
#pragma unroll
  for (int off = 32; off; off >>= 1) {
    s0 += __shfl_xor(s0, off);
    s1 += __shfl_xor(s1, off);
  }
  if (lane == 0) {
    bool keep = u_edge[wid] > PDROP;
    const float inv = 0.08838834764831845f;  // 1/sqrt(128)
    float a0 = s0 * inv, a1 = s1 * inv;
    alpha[wid * 2 + 0] = keep ? a0 : -INFINITY;
    alpha[wid * 2 + 1] = keep ? a1 : -INFINITY;
    if (keep) {
      atomicMax(&mkeys[d * 2 + 0], fkey(a0));
      atomicMax(&mkeys[d * 2 + 1], fkey(a1));
    }
  }
}

// ---- exp + denominator (thread per (edge,head)); exbuf aliases alpha ----
__global__ void exp_denom(const float* __restrict__ alpha,
                          const int* __restrict__ ei,
                          const unsigned* __restrict__ mkeys,
                          float* __restrict__ exbuf, float* __restrict__ denom) {
  int i = blockIdx.x * blockDim.x + threadIdx.x;
  if (i >= N_EDGES * NH) return;
  int eidx = i >> 1, h = i & 1;
  float a = alpha[i];
  float ex = 0.f;
  if (a > -1e30f) {
    int d = ei[N_EDGES + eidx];
    float m = fkey_dec(mkeys[d * 2 + h]);
    ex = __expf(a - m);
    atomicAdd(&denom[d * 2 + h], ex);
  }
  exbuf[i] = ex;
}

// ---- weighted scatter into out (wave per edge, out pre-init with skip) ----
__global__ __launch_bounds__(256) void scatter_out(
    const float* __restrict__ v, const bf16* __restrict__ e,
    const int* __restrict__ ei, const float* __restrict__ exbuf,
    const float* __restrict__ denom, const float* __restrict__ u_attn,
    float* __restrict__ out) {
  int wid = (blockIdx.x * blockDim.x + threadIdx.x) >> 6;
  int lane = threadIdx.x & 63;
  if (wid >= N_EDGES) return;
  int s = ei[wid], d = ei[N_EDGES + wid];
  float ex0 = exbuf[wid * 2 + 0], ex1 = exbuf[wid * 2 + 1];
  float at0 = ex0 / (denom[d * 2 + 0] + 1e-16f) *
              ((u_attn[wid * 2 + 0] > PDROP) ? (1.f / 0.9f) : 0.f);
  float at1 = ex1 / (denom[d * 2 + 1] + 1e-16f) *
              ((u_attn[wid * 2 + 1] > PDROP) ? (1.f / 0.9f) : 0.f);
  if (at0 == 0.f && at1 == 0.f) return;
  const float* vs = v + (size_t)s * DOUT;
  const bf16* ee = e + (size_t)wid * DOUT;
  float* od = out + (size_t)d * DOUT;
#pragma unroll
  for (int j = 0; j < 4; j++) {
    int c = lane + 64 * j;
    float att = (c < 128) ? at0 : at1;
    atomicAdd(&od[c], att * (vs[c] + __bfloat162float(ee[c])));
  }
}

extern "C" void kernel_launch(void* const* d_in, const int* in_sizes, int n_in,
                              void* d_out, int out_size, void* d_ws, size_t ws_size,
                              hipStream_t stream) {
  const float* x = (const float*)d_in[0];
  const float* last_update = (const float*)d_in[1];
  const int* ei = (const int*)d_in[2];
  const float* t = (const float*)d_in[3];
  const float* msg = (const float*)d_in[4];
  const float* u_edge = (const float*)d_in[5];
  const float* u_attn = (const float*)d_in[6];
  const float* time_w = (const float*)d_in[7];
  const float* time_b = (const float*)d_in[8];
  const float* Wq = (const float*)d_in[9];
  const float* bq = (const float*)d_in[10];
  const float* Wk = (const float*)d_in[11];
  const float* bk = (const float*)d_in[12];
  const float* Wv = (const float*)d_in[13];
  const float* bv = (const float*)d_in[14];
  const float* We = (const float*)d_in[15];
  const float* be = (const float*)d_in[16];
  const float* Ws = (const float*)d_in[17];
  const float* bs = (const float*)d_in[18];
  float* out = (float*)d_out;

  char* ws = (char*)d_ws;
  float* qbuf = (float*)(ws + 0);             // 20,480,000 B
  float* kbuf = (float*)(ws + 20480000);      // 20,480,000 B
  float* vbuf = (float*)(ws + 40960000);      // 20,480,000 B
  bf16* ebuf = (bf16*)(ws + 61440000);        // 102,400,000 B
  float* alphabuf = (float*)(ws + 163840000); // 1,600,000 B
  unsigned* mkeys = (unsigned*)(ws + 165440000); // 160,000 B
  float* denom = (float*)(ws + 165600000);    // 160,000 B
  // total ~165.8 MB

  init_md<<<(N_NODES * NH + 255) / 256, 256, 0, stream>>>(mkeys, denom);

  dim3 gn((N_NODES + 63) / 64, 4);
  gemm_nodes<<<gn, 256, 0, stream>>>(x, Wq, bq, qbuf);
  gemm_nodes<<<gn, 256, 0, stream>>>(x, Wk, bk, kbuf);
  gemm_nodes<<<gn, 256, 0, stream>>>(x, Wv, bv, vbuf);
  gemm_nodes<<<gn, 256, 0, stream>>>(x, Ws, bs, out);

  dim3 ge(N_EDGES / 64, 4);
  gemm_edges<<<ge, 256, 0, stream>>>(last_update, ei, t, msg, time_w, time_b,
                                     We, be, ebuf);

  alpha_max<<<(N_EDGES * 64) / 256, 256, 0, stream>>>(qbuf, kbuf, ebuf, ei,
                                                      u_edge, alphabuf, mkeys);
  exp_denom<<<(N_EDGES * 2 + 255) / 256, 256, 0, stream>>>(alphabuf, ei, mkeys,
                                                           alphabuf, denom);
  scatter_out<<<(N_EDGES * 64) / 256, 256, 0, stream>>>(vbuf, ebuf, ei,
                                                        alphabuf, denom,
                                                        u_attn, out);
}

// Round 2
// 813.439 us; speedup vs baseline: 1.0364x; 1.0364x over previous
//
#include <hip/hip_runtime.h>

#define NND 20000
#define NE 200000
#define PDROP 0.1f

typedef unsigned short u16;
typedef __bf16 bf16x8 __attribute__((ext_vector_type(8)));
typedef float f32x4 __attribute__((ext_vector_type(4)));

// ---- bf16 bit helpers (avoid __hip_bfloat16 class in __shared__) ----
__device__ __forceinline__ float b2f(u16 u) {
  unsigned v = ((unsigned)u) << 16;
  float f;
  __builtin_memcpy(&f, &v, 4);
  return f;
}
__device__ __forceinline__ u16 f2b(float f) {
  unsigned x;
  __builtin_memcpy(&x, &f, 4);
  unsigned r = x + 0x7fffu + ((x >> 16) & 1u);
  return (u16)(r >> 16);
}

// ---- ordered-uint encoding for float atomicMax ----
__device__ __forceinline__ unsigned fkey(float f) {
  unsigned u = __float_as_uint(f);
  return (u & 0x80000000u) ? ~u : (u | 0x80000000u);
}
__device__ __forceinline__ float fkey_dec(unsigned k) {
  return (k & 0x80000000u) ? __uint_as_float(k ^ 0x80000000u)
                           : __uint_as_float(~k);
}

__global__ void init_md(unsigned* __restrict__ mkeys, float* __restrict__ denom) {
  int i = blockIdx.x * blockDim.x + threadIdx.x;
  if (i < NND * 2) {
    mkeys[i] = 0x007FFFFFu;  // fkey(-inf)
    denom[i] = 0.f;
  }
}

__global__ void convert_x(const float* __restrict__ x, u16* __restrict__ xb) {
  int i = blockIdx.x * blockDim.x + threadIdx.x;  // one float4 per thread
  if (i < NND * 256 / 4) {
    float4 v = ((const float4*)x)[i];
    ushort4 o;
    o.x = f2b(v.x); o.y = f2b(v.y); o.z = f2b(v.z); o.w = f2b(v.w);
    ((ushort4*)xb)[i] = o;
  }
}

struct WTArgs {
  const float* W[5];
  u16* WT[5];
};
__global__ void convert_wT(WTArgs a) {
  int gid = blockIdx.x * blockDim.x + threadIdx.x;
  if (gid >= 5 * 65536) return;
  int w = gid >> 16, r = gid & 65535;
  int n = r >> 8, k = r & 255;
  a.WT[w][n * 256 + k] = f2b(a.W[w][k * 256 + n]);
}

__global__ void build_relt(const float* __restrict__ last_update,
                           const int* __restrict__ ei, const float* __restrict__ t,
                           float* __restrict__ relt) {
  int e = blockIdx.x * blockDim.x + threadIdx.x;
  if (e < NE) relt[e] = last_update[ei[e]] - t[e];
}

// ---- shared MFMA compute: 4 waves, each 64x64 of a 128x128 tile ----
__device__ __forceinline__ void mfma_tile(const u16 (*As)[72], const u16 (*Bs)[72],
                                          f32x4 acc[4][4], int wm, int wn,
                                          int fr, int fg) {
#pragma unroll
  for (int ks = 0; ks < 2; ks++) {
    bf16x8 a[4], b[4];
#pragma unroll
    for (int i = 0; i < 4; i++)
      a[i] = *(const bf16x8*)&As[wm * 64 + i * 16 + fr][ks * 32 + fg * 8];
#pragma unroll
    for (int j = 0; j < 4; j++)
      b[j] = *(const bf16x8*)&Bs[wn * 64 + j * 16 + fr][ks * 32 + fg * 8];
#pragma unroll
    for (int i = 0; i < 4; i++)
#pragma unroll
      for (int j = 0; j < 4; j++)
        acc[i][j] = __builtin_amdgcn_mfma_f32_16x16x32_bf16(a[i], b[j], acc[i][j], 0, 0, 0);
  }
}

// ---- fused node GEMM: y in [0,8): w=y>>1 selects {Wq,Wk,Wv,Ws}, y&1 col half ----
struct NodeArgs {
  const u16* BT[4];
  const float* bias[4];
  u16* outb[2];   // q, k (bf16)
  float* outf[2]; // v, skip->d_out (f32)
};
__global__ __launch_bounds__(256) void gemm_node(const u16* __restrict__ xb,
                                                 NodeArgs args) {
  __shared__ __attribute__((aligned(16))) u16 As[128][72];
  __shared__ __attribute__((aligned(16))) u16 Bs[128][72];
  const int tid = threadIdx.x;
  const int w = blockIdx.y >> 1;
  const int col0 = (blockIdx.y & 1) * 128;
  const int row0 = blockIdx.x * 128;
  const u16* BT = args.BT[w];
  const float* bias = args.bias[w];
  const int wid = tid >> 6, lane = tid & 63;
  const int wm = wid >> 1, wn = wid & 1;
  const int fr = lane & 15, fg = lane >> 4;
  f32x4 acc[4][4] = {};
  for (int k0 = 0; k0 < 256; k0 += 64) {
#pragma unroll
    for (int i = 0; i < 4; i++) {
      int idx = tid + i * 256;
      int row = idx >> 3, vc = idx & 7;
      int g = row0 + row;
      uint4 v = make_uint4(0, 0, 0, 0);
      if (g < NND) v = *(const uint4*)&xb[(size_t)g * 256 + k0 + vc * 8];
      *(uint4*)&As[row][vc * 8] = v;
      *(uint4*)&Bs[row][vc * 8] = *(const uint4*)&BT[(size_t)(col0 + row) * 256 + k0 + vc * 8];
    }
    __syncthreads();
    mfma_tile(As, Bs, acc, wm, wn, fr, fg);
    __syncthreads();
  }
#pragma unroll
  for (int mi = 0; mi < 4; mi++) {
#pragma unroll
    for (int rr = 0; rr < 4; rr++) {
      int grow = row0 + wm * 64 + mi * 16 + fg * 4 + rr;
      if (grow >= NND) continue;
#pragma unroll
      for (int ni = 0; ni < 4; ni++) {
        int gcol = col0 + wn * 64 + ni * 16 + fr;
        float val = acc[mi][ni][rr] + bias[gcol];
        if (w < 2)
          args.outb[w][(size_t)grow * 256 + gcol] = f2b(val);
        else
          args.outf[w - 2][(size_t)grow * 256 + gcol] = val;
      }
    }
  }
}

// ---- edge GEMM: A = [cos(relt*tw+tb) | msg] built on the fly, out bf16 ----
__global__ __launch_bounds__(256) void gemm_edge(
    const float* __restrict__ relt, const float* __restrict__ msg,
    const float* __restrict__ tw, const float* __restrict__ tb,
    const u16* __restrict__ WeT, const float* __restrict__ be,
    u16* __restrict__ ebuf) {
  __shared__ __attribute__((aligned(16))) u16 As[128][72];
  __shared__ __attribute__((aligned(16))) u16 Bs[128][72];
  __shared__ float relt_s[128];
  const int tid = threadIdx.x;
  const int col0 = blockIdx.y * 128;
  const int row0 = blockIdx.x * 128;
  if (tid < 128) {
    int e = row0 + tid;
    relt_s[tid] = (e < NE) ? relt[e] : 0.f;
  }
  __syncthreads();
  const int wid = tid >> 6, lane = tid & 63;
  const int wm = wid >> 1, wn = wid & 1;
  const int fr = lane & 15, fg = lane >> 4;
  const int vc = tid & 7, rbase = tid >> 3;
  f32x4 acc[4][4] = {};
  for (int k0 = 0; k0 < 256; k0 += 64) {
    int k8 = k0 + vc * 8;
    bool cosfull = (k8 + 7 < 100);
    bool msgfull = (k8 >= 100);
    float tww[8], tbb[8];
    if (cosfull) {
      float4 w0 = *(const float4*)&tw[k8], w1 = *(const float4*)&tw[k8 + 4];
      float4 c0 = *(const float4*)&tb[k8], c1 = *(const float4*)&tb[k8 + 4];
      tww[0] = w0.x; tww[1] = w0.y; tww[2] = w0.z; tww[3] = w0.w;
      tww[4] = w1.x; tww[5] = w1.y; tww[6] = w1.z; tww[7] = w1.w;
      tbb[0] = c0.x; tbb[1] = c0.y; tbb[2] = c0.z; tbb[3] = c0.w;
      tbb[4] = c1.x; tbb[5] = c1.y; tbb[6] = c1.z; tbb[7] = c1.w;
    }
#pragma unroll
    for (int i = 0; i < 4; i++) {
      int r = rbase + i * 32;
      int er = row0 + r;
      float vals[8];
      if (cosfull) {
        float rt = relt_s[r];
#pragma unroll
        for (int j = 0; j < 8; j++) vals[j] = __cosf(rt * tww[j] + tbb[j]);
      } else if (msgfull) {
        float4 m0 = make_float4(0, 0, 0, 0), m1 = make_float4(0, 0, 0, 0);
        if (er < NE) {
          const float4* mp = (const float4*)&msg[(size_t)er * 156 + (k8 - 100)];
          m0 = mp[0]; m1 = mp[1];
        }
        vals[0] = m0.x; vals[1] = m0.y; vals[2] = m0.z; vals[3] = m0.w;
        vals[4] = m1.x; vals[5] = m1.y; vals[6] = m1.z; vals[7] = m1.w;
      } else {  // k8 == 96: cols 96..103 mixed
        float rt = relt_s[r];
#pragma unroll
        for (int j = 0; j < 8; j++) {
          int k = k8 + j;
          if (k < 100)
            vals[j] = __cosf(rt * tw[k] + tb[k]);
          else
            vals[j] = (er < NE) ? msg[(size_t)er * 156 + k - 100] : 0.f;
        }
      }
      uint4 u;
      u.x = (unsigned)f2b(vals[0]) | ((unsigned)f2b(vals[1]) << 16);
      u.y = (unsigned)f2b(vals[2]) | ((unsigned)f2b(vals[3]) << 16);
      u.z = (unsigned)f2b(vals[4]) | ((unsigned)f2b(vals[5]) << 16);
      u.w = (unsigned)f2b(vals[6]) | ((unsigned)f2b(vals[7]) << 16);
      *(uint4*)&As[r][vc * 8] = u;
    }
#pragma unroll
    for (int i = 0; i < 4; i++) {
      int idx = tid + i * 256;
      int row = idx >> 3, v8 = idx & 7;
      *(uint4*)&Bs[row][v8 * 8] = *(const uint4*)&WeT[(size_t)(col0 + row) * 256 + k0 + v8 * 8];
    }
    __syncthreads();
    mfma_tile(As, Bs, acc, wm, wn, fr, fg);
    __syncthreads();
  }
#pragma unroll
  for (int mi = 0; mi < 4; mi++) {
#pragma unroll
    for (int rr = 0; rr < 4; rr++) {
      int er = row0 + wm * 64 + mi * 16 + fg * 4 + rr;
      if (er >= NE) continue;
#pragma unroll
      for (int ni = 0; ni < 4; ni++) {
        int gcol = col0 + wn * 64 + ni * 16 + fr;
        ebuf[(size_t)er * 256 + gcol] = f2b(acc[mi][ni][rr] + be[gcol]);
      }
    }
  }
}

// ---- per-edge logits + segment max (wave per edge; lane owns 4 cols) ----
__global__ __launch_bounds__(256) void alpha_max(
    const u16* __restrict__ q, const u16* __restrict__ k,
    const u16* __restrict__ e, const int* __restrict__ ei,
    const float* __restrict__ u_edge, float* __restrict__ alpha,
    unsigned* __restrict__ mkeys) {
  int wid = (blockIdx.x * blockDim.x + threadIdx.x) >> 6;
  int lane = threadIdx.x & 63;
  if (wid >= NE) return;
  int s = ei[wid];
  int d = ei[NE + wid];
  int c0 = lane * 4;
  ushort4 qv = *(const ushort4*)&q[(size_t)d * 256 + c0];
  ushort4 kv = *(const ushort4*)&k[(size_t)s * 256 + c0];
  ushort4 ev = *(const ushort4*)&e[(size_t)wid * 256 + c0];
  float p = b2f(qv.x) * (b2f(kv.x) + b2f(ev.x)) +
            b2f(qv.y) * (b2f(kv.y) + b2f(ev.y)) +
            b2f(qv.z) * (b2f(kv.z) + b2f(ev.z)) +
            b2f(qv.w) * (b2f(kv.w) + b2f(ev.w));
#pragma unroll
  for (int off = 16; off; off >>= 1) p += __shfl_xor(p, off);
  if ((lane & 31) == 0) {
    int h = lane >> 5;
    bool keep = u_edge[wid] > PDROP;
    float a = p * 0.08838834764831845f;  // 1/sqrt(128)
    alpha[wid * 2 + h] = keep ? a : -INFINITY;
    if (keep) atomicMax(&mkeys[d * 2 + h], fkey(a));
  }
}

__global__ void exp_denom(const float* __restrict__ alpha,
                          const int* __restrict__ ei,
                          const unsigned* __restrict__ mkeys,
                          float* __restrict__ exbuf, float* __restrict__ denom) {
  int i = blockIdx.x * blockDim.x + threadIdx.x;
  if (i >= NE * 2) return;
  int eidx = i >> 1, h = i & 1;
  float a = alpha[i];
  float ex = 0.f;
  if (a > -1e30f) {
    int d = ei[NE + eidx];
    float m = fkey_dec(mkeys[d * 2 + h]);
    ex = __expf(a - m);
    atomicAdd(&denom[d * 2 + h], ex);
  }
  exbuf[i] = ex;
}

__global__ __launch_bounds__(256) void scatter_out(
    const float* __restrict__ v, const u16* __restrict__ e,
    const int* __restrict__ ei, const float* __restrict__ exbuf,
    const float* __restrict__ denom, const float* __restrict__ u_attn,
    float* __restrict__ out) {
  int wid = (blockIdx.x * blockDim.x + threadIdx.x) >> 6;
  int lane = threadIdx.x & 63;
  if (wid >= NE) return;
  int s = ei[wid], d = ei[NE + wid];
  int c0 = lane * 4;
  int h = lane >> 5;
  float ex = exbuf[wid * 2 + h];
  float at = ex / (denom[d * 2 + h] + 1e-16f) *
             ((u_attn[wid * 2 + h] > PDROP) ? (1.f / 0.9f) : 0.f);
  if (at != 0.f) {
    float4 vv = *(const float4*)&v[(size_t)s * 256 + c0];
    ushort4 ev = *(const ushort4*)&e[(size_t)wid * 256 + c0];
    float* od = out + (size_t)d * 256 + c0;
    atomicAdd(&od[0], at * (vv.x + b2f(ev.x)));
    atomicAdd(&od[1], at * (vv.y + b2f(ev.y)));
    atomicAdd(&od[2], at * (vv.z + b2f(ev.z)));
    atomicAdd(&od[3], at * (vv.w + b2f(ev.w)));
  }
}

extern "C" void kernel_launch(void* const* d_in, const int* in_sizes, int n_in,
                              void* d_out, int out_size, void* d_ws, size_t ws_size,
                              hipStream_t stream) {
  const float* x = (const float*)d_in[0];
  const float* last_update = (const float*)d_in[1];
  const int* ei = (const int*)d_in[2];
  const float* t = (const float*)d_in[3];
  const float* msg = (const float*)d_in[4];
  const float* u_edge = (const float*)d_in[5];
  const float* u_attn = (const float*)d_in[6];
  const float* time_w = (const float*)d_in[7];
  const float* time_b = (const float*)d_in[8];
  const float* Wq = (const float*)d_in[9];
  const float* bq = (const float*)d_in[10];
  const float* Wk = (const float*)d_in[11];
  const float* bk = (const float*)d_in[12];
  const float* Wv = (const float*)d_in[13];
  const float* bv = (const float*)d_in[14];
  const float* We = (const float*)d_in[15];
  const float* be = (const float*)d_in[16];
  const float* Ws = (const float*)d_in[17];
  const float* bs = (const float*)d_in[18];
  float* out = (float*)d_out;

  char* ws = (char*)d_ws;
  u16* xb = (u16*)(ws + 0);                    // 10,240,000
  u16* WT0 = (u16*)(ws + 10240000);            // 5 x 131,072 = 655,360
  float* relt = (float*)(ws + 10895360);       // 800,000
  u16* qb = (u16*)(ws + 11695360);             // 10,240,000
  u16* kb = (u16*)(ws + 21935360);             // 10,240,000
  float* vb = (float*)(ws + 32175360);         // 20,480,000
  u16* ebuf = (u16*)(ws + 52655360);           // 102,400,000
  float* alphabuf = (float*)(ws + 155055360);  // 1,600,000
  unsigned* mkeys = (unsigned*)(ws + 156655360);  // 160,000
  float* denom = (float*)(ws + 156815360);     // 160,000
  // total 156,975,360 B

  init_md<<<(NND * 2 + 255) / 256, 256, 0, stream>>>(mkeys, denom);

  WTArgs wa;
  wa.W[0] = Wq; wa.W[1] = Wk; wa.W[2] = Wv; wa.W[3] = Ws; wa.W[4] = We;
  for (int i = 0; i < 5; i++) wa.WT[i] = WT0 + (size_t)i * 65536;
  convert_wT<<<(5 * 65536 + 255) / 256, 256, 0, stream>>>(wa);
  convert_x<<<(NND * 64 + 255) / 256, 256, 0, stream>>>(x, xb);
  build_relt<<<(NE + 255) / 256, 256, 0, stream>>>(last_update, ei, t, relt);

  NodeArgs na;
  na.BT[0] = wa.WT[0]; na.BT[1] = wa.WT[1]; na.BT[2] = wa.WT[2]; na.BT[3] = wa.WT[3];
  na.bias[0] = bq; na.bias[1] = bk; na.bias[2] = bv; na.bias[3] = bs;
  na.outb[0] = qb; na.outb[1] = kb;
  na.outf[0] = vb; na.outf[1] = out;
  dim3 gn((NND + 127) / 128, 8);
  gemm_node<<<gn, 256, 0, stream>>>(xb, na);

  dim3 ge((NE + 127) / 128, 2);
  gemm_edge<<<ge, 256, 0, stream>>>(relt, msg, time_w, time_b, wa.WT[4], be, ebuf);

  alpha_max<<<(NE * 64) / 256, 256, 0, stream>>>(qb, kb, ebuf, ei, u_edge,
                                                 alphabuf, mkeys);
  exp_denom<<<(NE * 2 + 255) / 256, 256, 0, stream>>>(alphabuf, ei, mkeys,
                                                      alphabuf, denom);
  scatter_out<<<(NE * 64) / 256, 256, 0, stream>>>(vb, ebuf, ei, alphabuf,
                                                   denom, u_attn, out);
}

// Round 3
// 364.845 us; speedup vs baseline: 2.3108x; 2.2295x over previous
//
#include <hip/hip_runtime.h>

#define NND 20000
#define NE 200000
#define PDROP 0.1f

typedef unsigned short u16;
typedef __bf16 bf16x8 __attribute__((ext_vector_type(8)));
typedef float f32x4 __attribute__((ext_vector_type(4)));

__device__ __forceinline__ float b2f(u16 u) {
  unsigned v = ((unsigned)u) << 16;
  float f;
  __builtin_memcpy(&f, &v, 4);
  return f;
}
__device__ __forceinline__ u16 f2b(float f) {
  unsigned x;
  __builtin_memcpy(&x, &f, 4);
  unsigned r = x + 0x7fffu + ((x >> 16) & 1u);
  return (u16)(r >> 16);
}

__global__ void convert_x(const float* __restrict__ x, u16* __restrict__ xb) {
  int i = blockIdx.x * blockDim.x + threadIdx.x;
  if (i < NND * 256 / 4) {
    float4 v = ((const float4*)x)[i];
    ushort4 o;
    o.x = f2b(v.x); o.y = f2b(v.y); o.z = f2b(v.z); o.w = f2b(v.w);
    ((ushort4*)xb)[i] = o;
  }
}

struct WTArgs {
  const float* W[5];
  u16* WT[5];
};
__global__ void convert_wT(WTArgs a) {
  int gid = blockIdx.x * blockDim.x + threadIdx.x;
  if (gid >= 5 * 65536) return;
  int w = gid >> 16, r = gid & 65535;
  int n = r >> 8, k = r & 255;
  a.WT[w][n * 256 + k] = f2b(a.W[w][k * 256 + n]);
}

__global__ void build_relt(const float* __restrict__ last_update,
                           const int* __restrict__ ei, const float* __restrict__ t,
                           float* __restrict__ relt) {
  int e = blockIdx.x * blockDim.x + threadIdx.x;
  if (e < NE) relt[e] = last_update[ei[e]] - t[e];
}

// ---- CSR build over dst ----
__global__ void zero2(int* __restrict__ cnt, int* __restrict__ cur) {
  int i = blockIdx.x * blockDim.x + threadIdx.x;
  if (i < NND) { cnt[i] = 0; cur[i] = 0; }
}
__global__ void csr_count(const int* __restrict__ ei, int* __restrict__ cnt) {
  int e = blockIdx.x * blockDim.x + threadIdx.x;
  if (e < NE) atomicAdd(&cnt[ei[NE + e]], 1);
}
__global__ __launch_bounds__(1024) void scan_rowptr(const int* __restrict__ cnt,
                                                    int* __restrict__ rowptr) {
  __shared__ int sums[1024];
  const int tid = threadIdx.x;
  const int base = tid * 20;
  int local[20];
  int run = 0;
#pragma unroll
  for (int i = 0; i < 20; i++) {
    int idx = base + i;
    local[i] = run;
    run += (idx < NND) ? cnt[idx] : 0;
  }
  sums[tid] = run;
  __syncthreads();
  for (int off = 1; off < 1024; off <<= 1) {
    int v = (tid >= off) ? sums[tid - off] : 0;
    __syncthreads();
    sums[tid] += v;
    __syncthreads();
  }
  int prev = (tid > 0) ? sums[tid - 1] : 0;
#pragma unroll
  for (int i = 0; i < 20; i++) {
    int idx = base + i;
    if (idx < NND) rowptr[idx] = prev + local[i];
  }
  if (tid == 1023) rowptr[NND] = sums[1023];
}
__global__ void csr_fill(const int* __restrict__ ei, const int* __restrict__ rowptr,
                         int* __restrict__ cur, int* __restrict__ elist) {
  int e = blockIdx.x * blockDim.x + threadIdx.x;
  if (e < NE) {
    int d = ei[NE + e];
    int pos = rowptr[d] + atomicAdd(&cur[d], 1);
    elist[pos] = e;
  }
}

// ---- shared MFMA compute: 4 waves, each 64x64 of a 128x128 tile ----
__device__ __forceinline__ void mfma_tile(const u16 (*As)[72], const u16 (*Bs)[72],
                                          f32x4 acc[4][4], int wm, int wn,
                                          int fr, int fg) {
#pragma unroll
  for (int ks = 0; ks < 2; ks++) {
    bf16x8 a[4], b[4];
#pragma unroll
    for (int i = 0; i < 4; i++)
      a[i] = *(const bf16x8*)&As[wm * 64 + i * 16 + fr][ks * 32 + fg * 8];
#pragma unroll
    for (int j = 0; j < 4; j++)
      b[j] = *(const bf16x8*)&Bs[wn * 64 + j * 16 + fr][ks * 32 + fg * 8];
#pragma unroll
    for (int i = 0; i < 4; i++)
#pragma unroll
      for (int j = 0; j < 4; j++)
        acc[i][j] = __builtin_amdgcn_mfma_f32_16x16x32_bf16(a[i], b[j], acc[i][j], 0, 0, 0);
  }
}

// ---- fused node GEMM: y in [0,8): w=y>>1 selects {Wq,Wk,Wv,Ws} ----
struct NodeArgs {
  const u16* BT[4];
  const float* bias[4];
  u16* outb[3];   // q, k, v (bf16)
  float* outf;    // skip -> d_out (f32)
};
__global__ __launch_bounds__(256) void gemm_node(const u16* __restrict__ xb,
                                                 NodeArgs args) {
  __shared__ __attribute__((aligned(16))) u16 As[128][72];
  __shared__ __attribute__((aligned(16))) u16 Bs[128][72];
  const int tid = threadIdx.x;
  const int w = blockIdx.y >> 1;
  const int col0 = (blockIdx.y & 1) * 128;
  const int row0 = blockIdx.x * 128;
  const u16* BT = args.BT[w];
  const float* bias = args.bias[w];
  const int wid = tid >> 6, lane = tid & 63;
  const int wm = wid >> 1, wn = wid & 1;
  const int fr = lane & 15, fg = lane >> 4;
  f32x4 acc[4][4] = {};
  for (int k0 = 0; k0 < 256; k0 += 64) {
#pragma unroll
    for (int i = 0; i < 4; i++) {
      int idx = tid + i * 256;
      int row = idx >> 3, vc = idx & 7;
      int g = row0 + row;
      uint4 v = make_uint4(0, 0, 0, 0);
      if (g < NND) v = *(const uint4*)&xb[(size_t)g * 256 + k0 + vc * 8];
      *(uint4*)&As[row][vc * 8] = v;
      *(uint4*)&Bs[row][vc * 8] = *(const uint4*)&BT[(size_t)(col0 + row) * 256 + k0 + vc * 8];
    }
    __syncthreads();
    mfma_tile(As, Bs, acc, wm, wn, fr, fg);
    __syncthreads();
  }
#pragma unroll
  for (int mi = 0; mi < 4; mi++) {
#pragma unroll
    for (int rr = 0; rr < 4; rr++) {
      int grow = row0 + wm * 64 + mi * 16 + fg * 4 + rr;
      if (grow >= NND) continue;
#pragma unroll
      for (int ni = 0; ni < 4; ni++) {
        int gcol = col0 + wn * 64 + ni * 16 + fr;
        float val = acc[mi][ni][rr] + bias[gcol];
        if (w < 3)
          args.outb[w][(size_t)grow * 256 + gcol] = f2b(val);
        else
          args.outf[(size_t)grow * 256 + gcol] = val;
      }
    }
  }
}

// ---- edge GEMM: A = [cos(relt*tw+tb) | msg] built on the fly, out bf16 ----
__global__ __launch_bounds__(256) void gemm_edge(
    const float* __restrict__ relt, const float* __restrict__ msg,
    const float* __restrict__ tw, const float* __restrict__ tb,
    const u16* __restrict__ WeT, const float* __restrict__ be,
    u16* __restrict__ ebuf) {
  __shared__ __attribute__((aligned(16))) u16 As[128][72];
  __shared__ __attribute__((aligned(16))) u16 Bs[128][72];
  __shared__ float relt_s[128];
  const int tid = threadIdx.x;
  const int col0 = blockIdx.y * 128;
  const int row0 = blockIdx.x * 128;
  if (tid < 128) {
    int e = row0 + tid;
    relt_s[tid] = (e < NE) ? relt[e] : 0.f;
  }
  __syncthreads();
  const int wid = tid >> 6, lane = tid & 63;
  const int wm = wid >> 1, wn = wid & 1;
  const int fr = lane & 15, fg = lane >> 4;
  const int vc = tid & 7, rbase = tid >> 3;
  f32x4 acc[4][4] = {};
  for (int k0 = 0; k0 < 256; k0 += 64) {
    int k8 = k0 + vc * 8;
    bool cosfull = (k8 + 7 < 100);
    bool msgfull = (k8 >= 100);
    float tww[8], tbb[8];
    if (cosfull) {
      float4 w0 = *(const float4*)&tw[k8], w1 = *(const float4*)&tw[k8 + 4];
      float4 c0 = *(const float4*)&tb[k8], c1 = *(const float4*)&tb[k8 + 4];
      tww[0] = w0.x; tww[1] = w0.y; tww[2] = w0.z; tww[3] = w0.w;
      tww[4] = w1.x; tww[5] = w1.y; tww[6] = w1.z; tww[7] = w1.w;
      tbb[0] = c0.x; tbb[1] = c0.y; tbb[2] = c0.z; tbb[3] = c0.w;
      tbb[4] = c1.x; tbb[5] = c1.y; tbb[6] = c1.z; tbb[7] = c1.w;
    }
#pragma unroll
    for (int i = 0; i < 4; i++) {
      int r = rbase + i * 32;
      int er = row0 + r;
      float vals[8];
      if (cosfull) {
        float rt = relt_s[r];
#pragma unroll
        for (int j = 0; j < 8; j++) vals[j] = __cosf(rt * tww[j] + tbb[j]);
      } else if (msgfull) {
        float4 m0 = make_float4(0, 0, 0, 0), m1 = make_float4(0, 0, 0, 0);
        if (er < NE) {
          const float4* mp = (const float4*)&msg[(size_t)er * 156 + (k8 - 100)];
          m0 = mp[0]; m1 = mp[1];
        }
        vals[0] = m0.x; vals[1] = m0.y; vals[2] = m0.z; vals[3] = m0.w;
        vals[4] = m1.x; vals[5] = m1.y; vals[6] = m1.z; vals[7] = m1.w;
      } else {
        float rt = relt_s[r];
#pragma unroll
        for (int j = 0; j < 8; j++) {
          int k = k8 + j;
          if (k < 100)
            vals[j] = __cosf(rt * tw[k] + tb[k]);
          else
            vals[j] = (er < NE) ? msg[(size_t)er * 156 + k - 100] : 0.f;
        }
      }
      uint4 u;
      u.x = (unsigned)f2b(vals[0]) | ((unsigned)f2b(vals[1]) << 16);
      u.y = (unsigned)f2b(vals[2]) | ((unsigned)f2b(vals[3]) << 16);
      u.z = (unsigned)f2b(vals[4]) | ((unsigned)f2b(vals[5]) << 16);
      u.w = (unsigned)f2b(vals[6]) | ((unsigned)f2b(vals[7]) << 16);
      *(uint4*)&As[r][vc * 8] = u;
    }
#pragma unroll
    for (int i = 0; i < 4; i++) {
      int idx = tid + i * 256;
      int row = idx >> 3, v8 = idx & 7;
      *(uint4*)&Bs[row][v8 * 8] = *(const uint4*)&WeT[(size_t)(col0 + row) * 256 + k0 + v8 * 8];
    }
    __syncthreads();
    mfma_tile(As, Bs, acc, wm, wn, fr, fg);
    __syncthreads();
  }
#pragma unroll
  for (int mi = 0; mi < 4; mi++) {
#pragma unroll
    for (int rr = 0; rr < 4; rr++) {
      int er = row0 + wm * 64 + mi * 16 + fg * 4 + rr;
      if (er >= NE) continue;
#pragma unroll
      for (int ni = 0; ni < 4; ni++) {
        int gcol = col0 + wn * 64 + ni * 16 + fr;
        ebuf[(size_t)er * 256 + gcol] = f2b(acc[mi][ni][rr] + be[gcol]);
      }
    }
  }
}

// ---- per-edge logits (dst-sorted order for q locality), no atomics ----
__global__ __launch_bounds__(256) void alpha_calc(
    const u16* __restrict__ q, const u16* __restrict__ k,
    const u16* __restrict__ e, const int* __restrict__ ei,
    const int* __restrict__ elist, const float* __restrict__ u_edge,
    float* __restrict__ alpha) {
  int widx = (blockIdx.x * blockDim.x + threadIdx.x) >> 6;
  int lane = threadIdx.x & 63;
  if (widx >= NE) return;
  int eid = elist[widx];
  int s = ei[eid];
  int d = ei[NE + eid];
  int c0 = lane * 4;
  ushort4 qv = *(const ushort4*)&q[(size_t)d * 256 + c0];
  ushort4 kv = *(const ushort4*)&k[(size_t)s * 256 + c0];
  ushort4 ev = *(const ushort4*)&e[(size_t)eid * 256 + c0];
  float p = b2f(qv.x) * (b2f(kv.x) + b2f(ev.x)) +
            b2f(qv.y) * (b2f(kv.y) + b2f(ev.y)) +
            b2f(qv.z) * (b2f(kv.z) + b2f(ev.z)) +
            b2f(qv.w) * (b2f(kv.w) + b2f(ev.w));
#pragma unroll
  for (int off = 16; off; off >>= 1) p += __shfl_xor(p, off);
  if ((lane & 31) == 0) {
    int h = lane >> 5;
    bool keep = u_edge[eid] > PDROP;
    float a = p * 0.08838834764831845f;  // 1/sqrt(128)
    alpha[eid * 2 + h] = keep ? a : -INFINITY;
  }
}

// ---- per-node gather: softmax stats + weighted sum, one wave per node ----
__global__ __launch_bounds__(256) void node_gather(
    const u16* __restrict__ vb, const u16* __restrict__ ebuf,
    const int* __restrict__ ei, const int* __restrict__ rowptr,
    const int* __restrict__ elist, const float* __restrict__ alpha,
    const float* __restrict__ u_attn, float* __restrict__ out) {
  int node = (blockIdx.x * blockDim.x + threadIdx.x) >> 6;
  int lane = threadIdx.x & 63;
  if (node >= NND) return;
  int beg = rowptr[node], end = rowptr[node + 1];
  int h = lane >> 5;
  int l32 = lane & 31;
  // pass 1: segment max and exp-sum per head (lanes 0-31: h0, 32-63: h1)
  float m = -INFINITY;
  for (int j = beg + l32; j < end; j += 32)
    m = fmaxf(m, alpha[elist[j] * 2 + h]);
#pragma unroll
  for (int off = 16; off; off >>= 1) m = fmaxf(m, __shfl_xor(m, off));
  float den = 0.f;
  if (m > -1e30f) {
    for (int j = beg + l32; j < end; j += 32) {
      float a = alpha[elist[j] * 2 + h];
      if (a > -1e30f) den += __expf(a - m);
    }
#pragma unroll
    for (int off = 16; off; off >>= 1) den += __shfl_xor(den, off);
  }
  float rden = 1.f / (den + 1e-16f);
  // pass 2: weighted accumulate
  float acc0 = 0.f, acc1 = 0.f, acc2 = 0.f, acc3 = 0.f;
  int c0 = lane * 4;
  for (int j = beg; j < end; j++) {
    int eid = elist[j];
    float a = alpha[eid * 2 + h];
    float at = 0.f;
    if (a > -1e30f)
      at = __expf(a - m) * rden *
           ((u_attn[eid * 2 + h] > PDROP) ? (1.f / 0.9f) : 0.f);
    if (__any(at != 0.f)) {
      int s = ei[eid];
      ushort4 vv = *(const ushort4*)&vb[(size_t)s * 256 + c0];
      ushort4 ev = *(const ushort4*)&ebuf[(size_t)eid * 256 + c0];
      acc0 += at * (b2f(vv.x) + b2f(ev.x));
      acc1 += at * (b2f(vv.y) + b2f(ev.y));
      acc2 += at * (b2f(vv.z) + b2f(ev.z));
      acc3 += at * (b2f(vv.w) + b2f(ev.w));
    }
  }
  float4* op = (float4*)&out[(size_t)node * 256 + c0];
  float4 sk = *op;  // skip connection written by gemm_node
  sk.x += acc0; sk.y += acc1; sk.z += acc2; sk.w += acc3;
  *op = sk;
}

extern "C" void kernel_launch(void* const* d_in, const int* in_sizes, int n_in,
                              void* d_out, int out_size, void* d_ws, size_t ws_size,
                              hipStream_t stream) {
  const float* x = (const float*)d_in[0];
  const float* last_update = (const float*)d_in[1];
  const int* ei = (const int*)d_in[2];
  const float* t = (const float*)d_in[3];
  const float* msg = (const float*)d_in[4];
  const float* u_edge = (const float*)d_in[5];
  const float* u_attn = (const float*)d_in[6];
  const float* time_w = (const float*)d_in[7];
  const float* time_b = (const float*)d_in[8];
  const float* Wq = (const float*)d_in[9];
  const float* bq = (const float*)d_in[10];
  const float* Wk = (const float*)d_in[11];
  const float* bk = (const float*)d_in[12];
  const float* Wv = (const float*)d_in[13];
  const float* bv = (const float*)d_in[14];
  const float* We = (const float*)d_in[15];
  const float* be = (const float*)d_in[16];
  const float* Ws = (const float*)d_in[17];
  const float* bs = (const float*)d_in[18];
  float* out = (float*)d_out;

  char* ws = (char*)d_ws;
  u16* xb = (u16*)(ws + 0);                     // 10,240,000
  u16* WT0 = (u16*)(ws + 10240000);             // 655,360
  float* relt = (float*)(ws + 10895360);        // 800,000
  u16* qb = (u16*)(ws + 11695360);              // 10,240,000
  u16* kb = (u16*)(ws + 21935360);              // 10,240,000
  u16* vb = (u16*)(ws + 32175360);              // 10,240,000
  u16* ebuf = (u16*)(ws + 42415360);            // 102,400,000
  float* alphabuf = (float*)(ws + 144815360);   // 1,600,000
  int* cnt = (int*)(ws + 146415360);            // 80,000
  int* cur = (int*)(ws + 146495360);            // 80,000
  int* rowptr = (int*)(ws + 146575360);         // 80,004
  int* elist = (int*)(ws + 146655368);          // 800,000
  // total ~147.5 MB

  // CSR build
  zero2<<<(NND + 255) / 256, 256, 0, stream>>>(cnt, cur);
  csr_count<<<(NE + 255) / 256, 256, 0, stream>>>(ei, cnt);
  scan_rowptr<<<1, 1024, 0, stream>>>(cnt, rowptr);
  csr_fill<<<(NE + 255) / 256, 256, 0, stream>>>(ei, rowptr, cur, elist);

  // precompute
  WTArgs wa;
  wa.W[0] = Wq; wa.W[1] = Wk; wa.W[2] = Wv; wa.W[3] = Ws; wa.W[4] = We;
  for (int i = 0; i < 5; i++) wa.WT[i] = WT0 + (size_t)i * 65536;
  convert_wT<<<(5 * 65536 + 255) / 256, 256, 0, stream>>>(wa);
  convert_x<<<(NND * 64 + 255) / 256, 256, 0, stream>>>(x, xb);
  build_relt<<<(NE + 255) / 256, 256, 0, stream>>>(last_update, ei, t, relt);

  // GEMMs
  NodeArgs na;
  na.BT[0] = wa.WT[0]; na.BT[1] = wa.WT[1]; na.BT[2] = wa.WT[2]; na.BT[3] = wa.WT[3];
  na.bias[0] = bq; na.bias[1] = bk; na.bias[2] = bv; na.bias[3] = bs;
  na.outb[0] = qb; na.outb[1] = kb; na.outb[2] = vb;
  na.outf = out;
  dim3 gn((NND + 127) / 128, 8);
  gemm_node<<<gn, 256, 0, stream>>>(xb, na);

  dim3 ge((NE + 127) / 128, 2);
  gemm_edge<<<ge, 256, 0, stream>>>(relt, msg, time_w, time_b, wa.WT[4], be, ebuf);

  // attention
  alpha_calc<<<(NE * 64) / 256, 256, 0, stream>>>(qb, kb, ebuf, ei, elist,
                                                  u_edge, alphabuf);
  node_gather<<<(NND * 64 + 255) / 256, 256, 0, stream>>>(
      vb, ebuf, ei, rowptr, elist, alphabuf, u_attn, out);
}

// Round 4
// 286.943 us; speedup vs baseline: 2.9382x; 1.2715x over previous
//
#include <hip/hip_runtime.h>

#define NND 20000
#define NE 200000
#define PDROP 0.1f

typedef unsigned short u16;
typedef __bf16 bf16x8 __attribute__((ext_vector_type(8)));
typedef float f32x4 __attribute__((ext_vector_type(4)));

__device__ __forceinline__ float b2f(u16 u) {
  unsigned v = ((unsigned)u) << 16;
  float f;
  __builtin_memcpy(&f, &v, 4);
  return f;
}
__device__ __forceinline__ u16 f2b(float f) {
  unsigned x;
  __builtin_memcpy(&x, &f, 4);
  unsigned r = x + 0x7fffu + ((x >> 16) & 1u);
  return (u16)(r >> 16);
}

__global__ void convert_x(const float* __restrict__ x, u16* __restrict__ xb) {
  int i = blockIdx.x * blockDim.x + threadIdx.x;
  if (i < NND * 256 / 4) {
    float4 v = ((const float4*)x)[i];
    ushort4 o;
    o.x = f2b(v.x); o.y = f2b(v.y); o.z = f2b(v.z); o.w = f2b(v.w);
    ((ushort4*)xb)[i] = o;
  }
}

// 0..3: Wq,Wk,Wv,Ws transposed; 4: We transposed (WeT); 5: We row-major (Web)
struct WTArgs {
  const float* W[6];
  u16* WT[6];
};
__global__ void convert_wT(WTArgs a) {
  int gid = blockIdx.x * blockDim.x + threadIdx.x;
  if (gid >= 6 * 65536) return;
  int w = gid >> 16, r = gid & 65535;
  if (w < 5) {
    int n = r >> 8, k = r & 255;
    a.WT[w][n * 256 + k] = f2b(a.W[w][k * 256 + n]);
  } else {
    a.WT[5][r] = f2b(a.W[5][r]);
  }
}

__global__ void build_relt(const float* __restrict__ last_update,
                           const int* __restrict__ ei, const float* __restrict__ t,
                           float* __restrict__ relt) {
  int e = blockIdx.x * blockDim.x + threadIdx.x;
  if (e < NE) relt[e] = last_update[ei[e]] - t[e];
}

// ---- CSR build over dst ----
__global__ void zero2(int* __restrict__ cnt, int* __restrict__ cur) {
  int i = blockIdx.x * blockDim.x + threadIdx.x;
  if (i < NND) { cnt[i] = 0; cur[i] = 0; }
}
__global__ void csr_count(const int* __restrict__ ei, int* __restrict__ cnt) {
  int e = blockIdx.x * blockDim.x + threadIdx.x;
  if (e < NE) atomicAdd(&cnt[ei[NE + e]], 1);
}
__global__ __launch_bounds__(1024) void scan_rowptr(const int* __restrict__ cnt,
                                                    int* __restrict__ rowptr) {
  __shared__ int sums[1024];
  const int tid = threadIdx.x;
  const int base = tid * 20;
  int local[20];
  int run = 0;
#pragma unroll
  for (int i = 0; i < 20; i++) {
    int idx = base + i;
    local[i] = run;
    run += (idx < NND) ? cnt[idx] : 0;
  }
  sums[tid] = run;
  __syncthreads();
  for (int off = 1; off < 1024; off <<= 1) {
    int v = (tid >= off) ? sums[tid - off] : 0;
    __syncthreads();
    sums[tid] += v;
    __syncthreads();
  }
  int prev = (tid > 0) ? sums[tid - 1] : 0;
#pragma unroll
  for (int i = 0; i < 20; i++) {
    int idx = base + i;
    if (idx < NND) rowptr[idx] = prev + local[i];
  }
  if (tid == 1023) rowptr[NND] = sums[1023];
}
__global__ void csr_fill(const int* __restrict__ ei, const int* __restrict__ rowptr,
                         int* __restrict__ cur, int* __restrict__ elist) {
  int e = blockIdx.x * blockDim.x + threadIdx.x;
  if (e < NE) {
    int d = ei[NE + e];
    int pos = rowptr[d] + atomicAdd(&cur[d], 1);
    elist[pos] = e;
  }
}

// ---- shared MFMA compute: 4 waves, each 64x64 of a 128x128 tile ----
__device__ __forceinline__ void mfma_tile(const u16 (*As)[72], const u16 (*Bs)[72],
                                          f32x4 acc[4][4], int wm, int wn,
                                          int fr, int fg) {
#pragma unroll
  for (int ks = 0; ks < 2; ks++) {
    bf16x8 a[4], b[4];
#pragma unroll
    for (int i = 0; i < 4; i++)
      a[i] = *(const bf16x8*)&As[wm * 64 + i * 16 + fr][ks * 32 + fg * 8];
#pragma unroll
    for (int j = 0; j < 4; j++)
      b[j] = *(const bf16x8*)&Bs[wn * 64 + j * 16 + fr][ks * 32 + fg * 8];
#pragma unroll
    for (int i = 0; i < 4; i++)
#pragma unroll
      for (int j = 0; j < 4; j++)
        acc[i][j] = __builtin_amdgcn_mfma_f32_16x16x32_bf16(a[i], b[j], acc[i][j], 0, 0, 0);
  }
}

// ---- fused node GEMM: y in [0,8): w=y>>1 selects {Wq,Wk,Wv,Ws} ----
struct NodeArgs {
  const u16* BT[4];
  const float* bias[4];
  u16* outb[3];   // q, k, v (bf16)
  float* outf;    // skip -> d_out (f32)
};
__global__ __launch_bounds__(256) void gemm_node(const u16* __restrict__ xb,
                                                 NodeArgs args) {
  __shared__ __attribute__((aligned(16))) u16 As[128][72];
  __shared__ __attribute__((aligned(16))) u16 Bs[128][72];
  const int tid = threadIdx.x;
  const int w = blockIdx.y >> 1;
  const int col0 = (blockIdx.y & 1) * 128;
  const int row0 = blockIdx.x * 128;
  const u16* BT = args.BT[w];
  const float* bias = args.bias[w];
  const int wid = tid >> 6, lane = tid & 63;
  const int wm = wid >> 1, wn = wid & 1;
  const int fr = lane & 15, fg = lane >> 4;
  f32x4 acc[4][4] = {};
  for (int k0 = 0; k0 < 256; k0 += 64) {
#pragma unroll
    for (int i = 0; i < 4; i++) {
      int idx = tid + i * 256;
      int row = idx >> 3, vc = idx & 7;
      int g = row0 + row;
      uint4 v = make_uint4(0, 0, 0, 0);
      if (g < NND) v = *(const uint4*)&xb[(size_t)g * 256 + k0 + vc * 8];
      *(uint4*)&As[row][vc * 8] = v;
      *(uint4*)&Bs[row][vc * 8] = *(const uint4*)&BT[(size_t)(col0 + row) * 256 + k0 + vc * 8];
    }
    __syncthreads();
    mfma_tile(As, Bs, acc, wm, wn, fr, fg);
    __syncthreads();
  }
#pragma unroll
  for (int mi = 0; mi < 4; mi++) {
#pragma unroll
    for (int rr = 0; rr < 4; rr++) {
      int grow = row0 + wm * 64 + mi * 16 + fg * 4 + rr;
      if (grow >= NND) continue;
#pragma unroll
      for (int ni = 0; ni < 4; ni++) {
        int gcol = col0 + wn * 64 + ni * 16 + fr;
        float val = acc[mi][ni][rr] + bias[gcol];
        if (w < 3)
          args.outb[w][(size_t)grow * 256 + gcol] = f2b(val);
        else
          args.outf[(size_t)grow * 256 + gcol] = val;
      }
    }
  }
}

// ---- qWe GEMM: qWe[n,h,j] = sum_c We[j, h*128+c] * q[n, h*128+c] ----
// y: h = y>>1, col-block = y&1. A = qb (K=128 slice), BT = Web rows.
__global__ __launch_bounds__(256) void gemm_qwe(const u16* __restrict__ qb,
                                                const u16* __restrict__ Web,
                                                u16* __restrict__ qWeb) {
  __shared__ __attribute__((aligned(16))) u16 As[128][72];
  __shared__ __attribute__((aligned(16))) u16 Bs[128][72];
  const int tid = threadIdx.x;
  const int h = blockIdx.y >> 1;
  const int col0 = (blockIdx.y & 1) * 128;
  const int row0 = blockIdx.x * 128;
  const int wid = tid >> 6, lane = tid & 63;
  const int wm = wid >> 1, wn = wid & 1;
  const int fr = lane & 15, fg = lane >> 4;
  f32x4 acc[4][4] = {};
  for (int k0 = 0; k0 < 128; k0 += 64) {
#pragma unroll
    for (int i = 0; i < 4; i++) {
      int idx = tid + i * 256;
      int row = idx >> 3, vc = idx & 7;
      int g = row0 + row;
      uint4 v = make_uint4(0, 0, 0, 0);
      if (g < NND) v = *(const uint4*)&qb[(size_t)g * 256 + h * 128 + k0 + vc * 8];
      *(uint4*)&As[row][vc * 8] = v;
      *(uint4*)&Bs[row][vc * 8] =
          *(const uint4*)&Web[(size_t)(col0 + row) * 256 + h * 128 + k0 + vc * 8];
    }
    __syncthreads();
    mfma_tile(As, Bs, acc, wm, wn, fr, fg);
    __syncthreads();
  }
#pragma unroll
  for (int mi = 0; mi < 4; mi++) {
#pragma unroll
    for (int rr = 0; rr < 4; rr++) {
      int grow = row0 + wm * 64 + mi * 16 + fg * 4 + rr;
      if (grow >= NND) continue;
#pragma unroll
      for (int ni = 0; ni < 4; ni++) {
        int gj = col0 + wn * 64 + ni * 16 + fr;
        qWeb[(size_t)grow * 512 + h * 256 + gj] = f2b(acc[mi][ni][rr]);
      }
    }
  }
}

// ---- fused per-node attention: alpha + softmax + gather, one wave/node ----
__global__ __launch_bounds__(256) void node_fused(
    const u16* __restrict__ qb, const u16* __restrict__ kb,
    const u16* __restrict__ vb, const u16* __restrict__ qWeb,
    const int* __restrict__ ei, const int* __restrict__ rowptr,
    const int* __restrict__ elist, const float* __restrict__ relt,
    const float* __restrict__ msg, const float* __restrict__ tw,
    const float* __restrict__ tb, const float* __restrict__ be,
    const float* __restrict__ u_edge, const float* __restrict__ u_attn,
    float* __restrict__ alphabuf, u16* __restrict__ aggb,
    float* __restrict__ out) {
  const int node = (blockIdx.x * blockDim.x + threadIdx.x) >> 6;
  const int lane = threadIdx.x & 63;
  const int c0 = lane * 4;      // channel / edge_attr index block
  const int hl = lane >> 5;     // this lane's head
  const int beg = rowptr[node], end = rowptr[node + 1];

  // per-node register loads
  ushort4 q4 = *(const ushort4*)&qb[(size_t)node * 256 + c0];
  float qf0 = b2f(q4.x), qf1 = b2f(q4.y), qf2 = b2f(q4.z), qf3 = b2f(q4.w);
  ushort4 w0v = *(const ushort4*)&qWeb[(size_t)node * 512 + c0];
  ushort4 w1v = *(const ushort4*)&qWeb[(size_t)node * 512 + 256 + c0];
  float qw00 = b2f(w0v.x), qw01 = b2f(w0v.y), qw02 = b2f(w0v.z), qw03 = b2f(w0v.w);
  float qw10 = b2f(w1v.x), qw11 = b2f(w1v.y), qw12 = b2f(w1v.z), qw13 = b2f(w1v.w);
  float4 bev = *(const float4*)&be[c0];
  // qbe per head (lanes 0-31 -> head0, 32-63 -> head1)
  float pb = qf0 * bev.x + qf1 * bev.y + qf2 * bev.z + qf3 * bev.w;
#pragma unroll
  for (int off = 16; off; off >>= 1) pb += __shfl_xor(pb, off);
  // time-encoder coefficients for edge_attr lanes (c0 < 100)
  float tw0 = 0, tw1 = 0, tw2 = 0, tw3 = 0, tb0 = 0, tb1 = 0, tb2 = 0, tb3 = 0;
  if (c0 < 100) {
    float4 a = *(const float4*)&tw[c0];
    float4 b = *(const float4*)&tb[c0];
    tw0 = a.x; tw1 = a.y; tw2 = a.z; tw3 = a.w;
    tb0 = b.x; tb1 = b.y; tb2 = b.z; tb3 = b.w;
  }
  const float inv = 0.08838834764831845f;  // 1/sqrt(128)

  // ---- pass 1: alpha per edge, track running max ----
  float m = -INFINITY;
  for (int j = beg; j < end; ++j) {
    int eid = elist[j];
    int s = ei[eid];
    float rt = relt[eid];
    ushort4 k4 = *(const ushort4*)&kb[(size_t)s * 256 + c0];
    float pqk = qf0 * b2f(k4.x) + qf1 * b2f(k4.y) + qf2 * b2f(k4.z) + qf3 * b2f(k4.w);
    float ea0, ea1, ea2, ea3;
    if (c0 < 100) {
      ea0 = __cosf(rt * tw0 + tb0); ea1 = __cosf(rt * tw1 + tb1);
      ea2 = __cosf(rt * tw2 + tb2); ea3 = __cosf(rt * tw3 + tb3);
    } else {
      float4 mm = *(const float4*)&msg[(size_t)eid * 156 + (c0 - 100)];
      ea0 = mm.x; ea1 = mm.y; ea2 = mm.z; ea3 = mm.w;
    }
    float pe0 = qw00 * ea0 + qw01 * ea1 + qw02 * ea2 + qw03 * ea3;
    float pe1 = qw10 * ea0 + qw11 * ea1 + qw12 * ea2 + qw13 * ea3;
    // joint reduce: z ends as sum(pe0) on lanes<32, sum(pe1) on lanes>=32
    float y0 = pe0 + __shfl_xor(pe0, 32);
    float y1 = pe1 + __shfl_xor(pe1, 32);
    float z = (lane < 32) ? y0 : y1;
#pragma unroll
    for (int off = 16; off; off >>= 1) {
      z += __shfl_xor(z, off);
      pqk += __shfl_xor(pqk, off);
    }
    bool keep = u_edge[eid] > PDROP;
    float a = keep ? (pqk + z + pb) * inv : -INFINITY;
    m = fmaxf(m, a);
    alphabuf[2 * j + hl] = a;  // all lanes store (same value per half)
  }

  // ---- pass 2: denom + weighted accumulation (unnormalized) ----
  float den = 0.f, sw = 0.f;
  float vc0 = 0, vc1 = 0, vc2 = 0, vc3 = 0;
  float g00 = 0, g01 = 0, g02 = 0, g03 = 0;
  float g10 = 0, g11 = 0, g12 = 0, g13 = 0;
  for (int j = beg; j < end; ++j) {
    int eid = elist[j];
    float a = alphabuf[2 * j + hl];
    float ex = (a > -1e30f) ? __expf(a - m) : 0.f;
    den += ex;
    float wa = ex * ((u_attn[(size_t)eid * 2 + hl] > PDROP) ? (1.f / 0.9f) : 0.f);
    float wo = __shfl_xor(wa, 32);
    float w0 = (lane < 32) ? wa : wo;
    float w1 = (lane < 32) ? wo : wa;
    if (w0 + w1 != 0.f) {  // wave-uniform
      int s = ei[eid];
      float rt = relt[eid];
      ushort4 v4 = *(const ushort4*)&vb[(size_t)s * 256 + c0];
      float ea0, ea1, ea2, ea3;
      if (c0 < 100) {
        ea0 = __cosf(rt * tw0 + tb0); ea1 = __cosf(rt * tw1 + tb1);
        ea2 = __cosf(rt * tw2 + tb2); ea3 = __cosf(rt * tw3 + tb3);
      } else {
        float4 mm = *(const float4*)&msg[(size_t)eid * 156 + (c0 - 100)];
        ea0 = mm.x; ea1 = mm.y; ea2 = mm.z; ea3 = mm.w;
      }
      vc0 += wa * b2f(v4.x); vc1 += wa * b2f(v4.y);
      vc2 += wa * b2f(v4.z); vc3 += wa * b2f(v4.w);
      g00 += w0 * ea0; g01 += w0 * ea1; g02 += w0 * ea2; g03 += w0 * ea3;
      g10 += w1 * ea0; g11 += w1 * ea1; g12 += w1 * ea2; g13 += w1 * ea3;
      sw += wa;
    }
  }
  float rden = 1.f / (den + 1e-16f);
  float ro = __shfl_xor(rden, 32);
  float r0 = (lane < 32) ? rden : ro;
  float r1 = (lane < 32) ? ro : rden;
  // out += (vagg + sw*be) * rden   (out holds skip from gemm_node)
  float4 o = *(float4*)&out[(size_t)node * 256 + c0];
  o.x += (vc0 + sw * bev.x) * rden;
  o.y += (vc1 + sw * bev.y) * rden;
  o.z += (vc2 + sw * bev.z) * rden;
  o.w += (vc3 + sw * bev.w) * rden;
  *(float4*)&out[(size_t)node * 256 + c0] = o;
  // agg (normalized) -> bf16, layout [h][n][256]
  ushort4 a0, a1;
  a0.x = f2b(g00 * r0); a0.y = f2b(g01 * r0); a0.z = f2b(g02 * r0); a0.w = f2b(g03 * r0);
  a1.x = f2b(g10 * r1); a1.y = f2b(g11 * r1); a1.z = f2b(g12 * r1); a1.w = f2b(g13 * r1);
  *(ushort4*)&aggb[(size_t)node * 256 + c0] = a0;
  *(ushort4*)&aggb[(size_t)(NND + node) * 256 + c0] = a1;
}

// ---- final GEMM: out[:, h*128 + c] += agg_h (Nx256) @ We_h (256x128) ----
__global__ __launch_bounds__(256) void gemm_final(const u16* __restrict__ aggb,
                                                  const u16* __restrict__ WeT,
                                                  float* __restrict__ out) {
  __shared__ __attribute__((aligned(16))) u16 As[128][72];
  __shared__ __attribute__((aligned(16))) u16 Bs[128][72];
  const int tid = threadIdx.x;
  const int h = blockIdx.y;
  const int row0 = blockIdx.x * 128;
  const u16* A = aggb + (size_t)h * NND * 256;
  const int wid = tid >> 6, lane = tid & 63;
  const int wm = wid >> 1, wn = wid & 1;
  const int fr = lane & 15, fg = lane >> 4;
  f32x4 acc[4][4] = {};
  for (int k0 = 0; k0 < 256; k0 += 64) {
#pragma unroll
    for (int i = 0; i < 4; i++) {
      int idx = tid + i * 256;
      int row = idx >> 3, vc = idx & 7;
      int g = row0 + row;
      uint4 v = make_uint4(0, 0, 0, 0);
      if (g < NND) v = *(const uint4*)&A[(size_t)g * 256 + k0 + vc * 8];
      *(uint4*)&As[row][vc * 8] = v;
      *(uint4*)&Bs[row][vc * 8] =
          *(const uint4*)&WeT[(size_t)(h * 128 + row) * 256 + k0 + vc * 8];
    }
    __syncthreads();
    mfma_tile(As, Bs, acc, wm, wn, fr, fg);
    __syncthreads();
  }
#pragma unroll
  for (int mi = 0; mi < 4; mi++) {
#pragma unroll
    for (int rr = 0; rr < 4; rr++) {
      int grow = row0 + wm * 64 + mi * 16 + fg * 4 + rr;
      if (grow >= NND) continue;
#pragma unroll
      for (int ni = 0; ni < 4; ni++) {
        int gcol = wn * 64 + ni * 16 + fr;
        out[(size_t)grow * 256 + h * 128 + gcol] += acc[mi][ni][rr];
      }
    }
  }
}

extern "C" void kernel_launch(void* const* d_in, const int* in_sizes, int n_in,
                              void* d_out, int out_size, void* d_ws, size_t ws_size,
                              hipStream_t stream) {
  const float* x = (const float*)d_in[0];
  const float* last_update = (const float*)d_in[1];
  const int* ei = (const int*)d_in[2];
  const float* t = (const float*)d_in[3];
  const float* msg = (const float*)d_in[4];
  const float* u_edge = (const float*)d_in[5];
  const float* u_attn = (const float*)d_in[6];
  const float* time_w = (const float*)d_in[7];
  const float* time_b = (const float*)d_in[8];
  const float* Wq = (const float*)d_in[9];
  const float* bq = (const float*)d_in[10];
  const float* Wk = (const float*)d_in[11];
  const float* bk = (const float*)d_in[12];
  const float* Wv = (const float*)d_in[13];
  const float* bv = (const float*)d_in[14];
  const float* We = (const float*)d_in[15];
  const float* be = (const float*)d_in[16];
  const float* Ws = (const float*)d_in[17];
  const float* bs = (const float*)d_in[18];
  float* out = (float*)d_out;

  char* ws = (char*)d_ws;
  u16* xb = (u16*)(ws + 0);                    // 10,240,000
  u16* WT0 = (u16*)(ws + 10240000);            // 6 x 131,072 = 786,432
  float* relt = (float*)(ws + 11026432);       // 800,000
  u16* qb = (u16*)(ws + 11826432);             // 10,240,000
  u16* kb = (u16*)(ws + 22066432);             // 10,240,000
  u16* vb = (u16*)(ws + 32306432);             // 10,240,000
  u16* qWeb = (u16*)(ws + 42546432);           // 20,480,000
  u16* aggb = (u16*)(ws + 63026432);           // 20,480,000
  float* alphabuf = (float*)(ws + 83506432);   // 1,600,000
  int* cnt = (int*)(ws + 85106432);            // 80,000
  int* cur = (int*)(ws + 85186432);            // 80,000
  int* rowptr = (int*)(ws + 85266432);         // 80,004
  int* elist = (int*)(ws + 85346448);          // 800,000
  // total ~86.1 MB

  // CSR build
  zero2<<<(NND + 255) / 256, 256, 0, stream>>>(cnt, cur);
  csr_count<<<(NE + 255) / 256, 256, 0, stream>>>(ei, cnt);
  scan_rowptr<<<1, 1024, 0, stream>>>(cnt, rowptr);
  csr_fill<<<(NE + 255) / 256, 256, 0, stream>>>(ei, rowptr, cur, elist);

  // precompute
  WTArgs wa;
  wa.W[0] = Wq; wa.W[1] = Wk; wa.W[2] = Wv; wa.W[3] = Ws; wa.W[4] = We; wa.W[5] = We;
  for (int i = 0; i < 6; i++) wa.WT[i] = WT0 + (size_t)i * 65536;
  convert_wT<<<(6 * 65536 + 255) / 256, 256, 0, stream>>>(wa);
  convert_x<<<(NND * 64 + 255) / 256, 256, 0, stream>>>(x, xb);
  build_relt<<<(NE + 255) / 256, 256, 0, stream>>>(last_update, ei, t, relt);

  // node projections (q,k,v bf16; skip f32 -> out)
  NodeArgs na;
  na.BT[0] = wa.WT[0]; na.BT[1] = wa.WT[1]; na.BT[2] = wa.WT[2]; na.BT[3] = wa.WT[3];
  na.bias[0] = bq; na.bias[1] = bk; na.bias[2] = bv; na.bias[3] = bs;
  na.outb[0] = qb; na.outb[1] = kb; na.outb[2] = vb;
  na.outf = out;
  dim3 gn((NND + 127) / 128, 8);
  gemm_node<<<gn, 256, 0, stream>>>(xb, na);

  // qWe[n,h,256] = We_h^T-projected q
  dim3 gq((NND + 127) / 128, 4);
  gemm_qwe<<<gq, 256, 0, stream>>>(qb, wa.WT[5], qWeb);

  // fused attention per node
  node_fused<<<NND / 4, 256, 0, stream>>>(qb, kb, vb, qWeb, ei, rowptr, elist,
                                          relt, msg, time_w, time_b, be, u_edge,
                                          u_attn, alphabuf, aggb, out);

  // out += agg_h @ We_h
  dim3 gf((NND + 127) / 128, 2);
  gemm_final<<<gf, 256, 0, stream>>>(aggb, wa.WT[4], out);
}